// Round 3
// baseline (254.128 us; speedup 1.0000x reference)
//
#include <hip/hip_runtime.h>

#define B_ 2
#define N_ 10000
#define E_ 150000
#define C_ 256
#define M_EDGE (B_*E_)   // 300000
#define M_NODE (B_*N_)   // 20000
#define EPS_ 1e-5f

typedef unsigned short u16;
typedef unsigned int   u32;
typedef __attribute__((ext_vector_type(8))) __bf16 bf16x8;
typedef __attribute__((ext_vector_type(4))) float  f32x4;

__device__ __forceinline__ u16 f2bf(float x) {
  union { float f; u32 u; } v; v.f = x;
  u32 r = v.u + 0x7FFFu + ((v.u >> 16) & 1u);   // RNE
  return (u16)(r >> 16);
}

__device__ __forceinline__ void async16(void* lds, const void* g) {
  __builtin_amdgcn_global_load_lds(
      (const __attribute__((address_space(1))) void*)g,
      (__attribute__((address_space(3))) void*)lds, 16, 0, 0);
}

// ---------------- init: zero counts + stats ----------------
__global__ void k_init(int* __restrict__ counts, float* __restrict__ stats) {
  int i = blockIdx.x * 256 + threadIdx.x;
  if (i < M_NODE) counts[i] = 0;
  if (i < 1024) stats[i] = 0.f;
}

// ---------------- features [B][C][N] f32 -> vf [B][N][C] bf16 ----------------
__global__ void k_transpose_feat(const float* __restrict__ f, u16* __restrict__ vf) {
  __shared__ float tile[32][33];
  int tx = threadIdx.x & 31, ty = threadIdx.x >> 5;
  int b = blockIdx.z, c0 = blockIdx.y * 32, n0 = blockIdx.x * 32;
  #pragma unroll
  for (int i = 0; i < 4; i++) {
    int c = c0 + ty + i*8, n = n0 + tx;
    tile[ty + i*8][tx] = (n < N_) ? f[((size_t)(b*C_ + c))*N_ + n] : 0.f;
  }
  __syncthreads();
  #pragma unroll
  for (int i = 0; i < 4; i++) {
    int n = n0 + ty + i*8, c = c0 + tx;
    if (n < N_) vf[((size_t)(b*N_ + n))*C_ + c] = f2bf(tile[tx][ty + i*8]);
  }
}

// ---------------- W_e[0:256][:], W_u -> transposed bf16 [Cout][K] ----------------
__global__ void k_transpose_w(const float* __restrict__ We, const float* __restrict__ Wu,
                              u16* __restrict__ WeT, u16* __restrict__ WuT) {
  __shared__ float tile[32][33];
  const float* src = blockIdx.z ? Wu : We;
  u16* dst = blockIdx.z ? WuT : WeT;
  int tx = threadIdx.x & 31, ty = threadIdx.x >> 5;
  int r0 = blockIdx.y * 32, c0 = blockIdx.x * 32;
  #pragma unroll
  for (int i = 0; i < 4; i++)
    tile[ty + i*8][tx] = src[(size_t)(r0 + ty + i*8)*C_ + c0 + tx];
  __syncthreads();
  #pragma unroll
  for (int i = 0; i < 4; i++)
    dst[(size_t)(c0 + ty + i*8)*C_ + r0 + tx] = f2bf(tile[tx][ty + i*8]);
}

// ---------------- histogram of dst ----------------
__global__ void k_hist(const int* __restrict__ edges, int* __restrict__ counts) {
  int i = blockIdx.x * 256 + threadIdx.x;
  if (i >= M_EDGE) return;
  int b = (i >= E_) ? 1 : 0;
  int e = i - b * E_;
  int d = edges[(size_t)(b*2 + 1)*E_ + e];
  atomicAdd(&counts[b*N_ + d], 1);
}

// ---------------- exclusive scan of counts (single block) ----------------
__global__ __launch_bounds__(1024)
void k_scan(const int* __restrict__ counts, int* __restrict__ offs, int* __restrict__ cursor) {
  __shared__ int part[1024];
  int t = threadIdx.x;
  int base = t * 20;
  int vals[20];
  if (t < 1000) {
    #pragma unroll
    for (int j = 0; j < 5; j++)
      *(int4*)&vals[j*4] = *(const int4*)&counts[base + j*4];
  } else {
    #pragma unroll
    for (int i = 0; i < 20; i++) vals[i] = 0;
  }
  int local[20];
  int s = 0;
  #pragma unroll
  for (int i = 0; i < 20; i++) { local[i] = s; s += vals[i]; }
  part[t] = s;
  __syncthreads();
  for (int d = 1; d < 1024; d <<= 1) {
    int v = (t >= d) ? part[t - d] : 0;
    __syncthreads();
    part[t] += v;
    __syncthreads();
  }
  int excl = (t == 0) ? 0 : part[t - 1];
  if (t < 1000) {
    #pragma unroll
    for (int j = 0; j < 5; j++) {
      int4 o;
      o.x = excl + local[j*4 + 0];
      o.y = excl + local[j*4 + 1];
      o.z = excl + local[j*4 + 2];
      o.w = excl + local[j*4 + 3];
      *(int4*)&offs[base + j*4]   = o;
      *(int4*)&cursor[base + j*4] = o;
    }
  }
}

// ---------------- scatter edges into CSR slots (packed descriptor) ----------------
__global__ void k_scatter(const int* __restrict__ edges, const float* __restrict__ xyz,
                          int* __restrict__ cursor, float4* __restrict__ ed) {
  int i = blockIdx.x * 256 + threadIdx.x;
  if (i >= M_EDGE) return;
  int b = (i >= E_) ? 1 : 0;
  int e = i - b * E_;
  int s = edges[(size_t)(b*2 + 0)*E_ + e];
  int d = edges[(size_t)(b*2 + 1)*E_ + e];
  const float* ps = xyz + ((size_t)(b*N_ + s))*3;
  const float* pd = xyz + ((size_t)(b*N_ + d))*3;
  int pos = atomicAdd(&cursor[b*N_ + d], 1);
  ed[pos] = make_float4(ps[0]-pd[0], ps[1]-pd[1], ps[2]-pd[2],
                        __int_as_float(b*N_ + s));
}

// ---------------- z GEMM: z = vf @ We[0:256] + be (f32 out) ----------------
__global__ __launch_bounds__(256)
void k_zgemm(const u16* __restrict__ A, const u16* __restrict__ WeT,
             const float* __restrict__ be, float* __restrict__ z)
{
  __shared__ __align__(16) u16 As[128*32];
  __shared__ __align__(16) u16 Bs[128*32];
  const int t  = threadIdx.x;
  const int n0 = blockIdx.x * 128;
  const int mb = blockIdx.y * 128;

  int r0 = mb + (t >> 2);      if (r0 >= M_NODE) r0 = 0;
  int r1 = mb + 64 + (t >> 2); if (r1 >= M_NODE) r1 = 0;
  const int ak = (((t & 3) ^ ((t >> 3) & 3)) << 3);
  const u16* asrc0 = A + (size_t)r0 * C_ + ak;
  const u16* asrc1 = A + (size_t)r1 * C_ + ak;
  const u16* bsrc0 = WeT + (size_t)(n0 + (t >> 2)) * C_ + ak;
  const u16* bsrc1 = WeT + (size_t)(n0 + 64 + (t >> 2)) * C_ + ak;

  const f32x4 zero = {0.f, 0.f, 0.f, 0.f};
  f32x4 acc[4][4];
  #pragma unroll
  for (int m = 0; m < 4; m++)
    #pragma unroll
    for (int n = 0; n < 4; n++) acc[m][n] = zero;

  const int lane = t & 63, wave = t >> 6;
  const int wr = wave >> 1, wc = wave & 1;
  const int lr = lane & 15, lch = lane >> 4;
  const int swz = (lr >> 1) & 3;

  for (int kk = 0; kk < 8; kk++) {
    const int k0 = kk * 32;
    async16(&As[t*8],        asrc0 + k0);
    async16(&As[(t+256)*8],  asrc1 + k0);
    async16(&Bs[t*8],        bsrc0 + k0);
    async16(&Bs[(t+256)*8],  bsrc1 + k0);
    __syncthreads();
    bf16x8 a[4], b[4];
    #pragma unroll
    for (int m = 0; m < 4; m++)
      a[m] = *(const bf16x8*)&As[(wr*64 + m*16 + lr)*32 + ((lch ^ swz) << 3)];
    #pragma unroll
    for (int n = 0; n < 4; n++)
      b[n] = *(const bf16x8*)&Bs[(wc*64 + n*16 + lr)*32 + ((lch ^ swz) << 3)];
    #pragma unroll
    for (int m = 0; m < 4; m++)
      #pragma unroll
      for (int n = 0; n < 4; n++)
        acc[m][n] = __builtin_amdgcn_mfma_f32_16x16x32_bf16(a[m], b[n], acc[m][n], 0, 0, 0);
    __syncthreads();
  }

  int gc[4]; float bias[4];
  #pragma unroll
  for (int n = 0; n < 4; n++) { int c = n0 + wc*64 + n*16 + lr; gc[n] = c; bias[n] = be[c]; }
  #pragma unroll
  for (int m = 0; m < 4; m++) {
    #pragma unroll
    for (int j = 0; j < 4; j++) {
      int r = mb + wr*64 + m*16 + lch*4 + j;
      if (r < M_NODE) {
        #pragma unroll
        for (int n = 0; n < 4; n++)
          z[(size_t)r * C_ + gc[n]] = acc[m][n][j] + bias[n];
      }
    }
  }
}

// ---------------- aggregation: one wave per node, depth-2 pipelined gather ----------------
__global__ __launch_bounds__(256)
void k_agg(const float* __restrict__ z, const float4* __restrict__ ed,
           const int* __restrict__ offs, const int* __restrict__ counts,
           const float* __restrict__ We, const float* __restrict__ ge,
           float* __restrict__ agg, float* __restrict__ esum, float* __restrict__ esumsq)
{
  const int lane = threadIdx.x & 63, wave = threadIdx.x >> 6;
  const int c0 = lane * 4;
  const float4 w0 = *(const float4*)&We[256*C_ + c0];
  const float4 w1 = *(const float4*)&We[257*C_ + c0];
  const float4 w2 = *(const float4*)&We[258*C_ + c0];
  const float4 gs = *(const float4*)&ge[c0];

  float ps[4] = {0.f,0.f,0.f,0.f};
  float pq[4] = {0.f,0.f,0.f,0.f};

  const int n = blockIdx.x * 4 + wave;        // grid = 5000 blocks -> exactly M_NODE waves
  const int start = offs[n], cnt = counts[n];
  float mx[4] = {-1.f,-1.f,-1.f,-1.f};        // y >= 0
  float mn[4] = {1e30f,1e30f,1e30f,1e30f};

  if (cnt > 0) {
    const int last = cnt - 1;
    auto ldd = [&](int k) -> float4 {
      return ed[start + (k < last ? k : last)];
    };
    auto zrow = [&](const float4& d) -> f32x4 {
      return *(const f32x4*)&z[(size_t)__float_as_int(d.w) * C_ + c0];
    };
    auto proc = [&](const float4& d, const f32x4& zv, int idx) {
      if (idx < cnt) {   // wave-uniform branch
        float y0 = fmaxf(fmaf(d.z, w2.x, fmaf(d.y, w1.x, fmaf(d.x, w0.x, zv.x))), 0.f);
        float y1 = fmaxf(fmaf(d.z, w2.y, fmaf(d.y, w1.y, fmaf(d.x, w0.y, zv.y))), 0.f);
        float y2 = fmaxf(fmaf(d.z, w2.z, fmaf(d.y, w1.z, fmaf(d.x, w0.z, zv.z))), 0.f);
        float y3 = fmaxf(fmaf(d.z, w2.w, fmaf(d.y, w1.w, fmaf(d.x, w0.w, zv.w))), 0.f);
        mx[0] = fmaxf(mx[0], y0); mn[0] = fminf(mn[0], y0); ps[0] += y0; pq[0] = fmaf(y0, y0, pq[0]);
        mx[1] = fmaxf(mx[1], y1); mn[1] = fminf(mn[1], y1); ps[1] += y1; pq[1] = fmaf(y1, y1, pq[1]);
        mx[2] = fmaxf(mx[2], y2); mn[2] = fminf(mn[2], y2); ps[2] += y2; pq[2] = fmaf(y2, y2, pq[2]);
        mx[3] = fmaxf(mx[3], y3); mn[3] = fminf(mn[3], y3); ps[3] += y3; pq[3] = fmaf(y3, y3, pq[3]);
      }
    };

    // prologue: chunk A descs + z, chunk B descs
    float4 dA0 = ldd(0), dA1 = ldd(1), dA2 = ldd(2), dA3 = ldd(3);
    f32x4  zA0 = zrow(dA0), zA1 = zrow(dA1), zA2 = zrow(dA2), zA3 = zrow(dA3);
    float4 dB0 = ldd(4), dB1 = ldd(5), dB2 = ldd(6), dB3 = ldd(7);

    for (int i = 0; i < cnt; i += 8) {
      // issue z for chunk B (in flight across A-compute)
      f32x4 zB0 = zrow(dB0), zB1 = zrow(dB1), zB2 = zrow(dB2), zB3 = zrow(dB3);
      // compute chunk A
      proc(dA0, zA0, i+0); proc(dA1, zA1, i+1); proc(dA2, zA2, i+2); proc(dA3, zA3, i+3);
      // load next-A descriptors (i+8..i+11)
      dA0 = ldd(i+8); dA1 = ldd(i+9); dA2 = ldd(i+10); dA3 = ldd(i+11);
      // compute chunk B (zB in flight since top)
      proc(dB0, zB0, i+4); proc(dB1, zB1, i+5); proc(dB2, zB2, i+6); proc(dB3, zB3, i+7);
      // load next-B descriptors (i+12..i+15)
      dB0 = ldd(i+12); dB1 = ldd(i+13); dB2 = ldd(i+14); dB3 = ldd(i+15);
      // issue z for next chunk A (in flight across loop backedge)
      zA0 = zrow(dA0); zA1 = zrow(dA1); zA2 = zrow(dA2); zA3 = zrow(dA3);
    }
  }

  float4 outv;
  outv.x = (gs.x >= 0.f) ? mx[0] : mn[0];
  outv.y = (gs.y >= 0.f) ? mx[1] : mn[1];
  outv.z = (gs.z >= 0.f) ? mx[2] : mn[2];
  outv.w = (gs.w >= 0.f) ? mx[3] : mn[3];
  *(float4*)&agg[(size_t)n * C_ + c0] = outv;

  // block-level stats reduction -> one atomicAdd per col
  __shared__ float red[4][256];
  #pragma unroll
  for (int j = 0; j < 4; j++) red[wave][c0 + j] = ps[j];
  __syncthreads();
  if (threadIdx.x < 256) {
    float s = red[0][threadIdx.x] + red[1][threadIdx.x] + red[2][threadIdx.x] + red[3][threadIdx.x];
    atomicAdd(&esum[threadIdx.x], s);
  }
  __syncthreads();
  #pragma unroll
  for (int j = 0; j < 4; j++) red[wave][c0 + j] = pq[j];
  __syncthreads();
  if (threadIdx.x < 256) {
    float s = red[0][threadIdx.x] + red[1][threadIdx.x] + red[2][threadIdx.x] + red[3][threadIdx.x];
    atomicAdd(&esumsq[threadIdx.x], s);
  }
}

// ---------------- BN stats -> scale/shift ----------------
__global__ void k_stats(const float* __restrict__ sum, const float* __restrict__ sumsq,
                        const float* __restrict__ g, const float* __restrict__ beta,
                        float cnt, float* __restrict__ scale, float* __restrict__ shift) {
  int c = threadIdx.x;
  float m = sum[c] / cnt;
  float v = sumsq[c] / cnt - m*m;
  v = fmaxf(v, 0.f);
  float s = g[c] * rsqrtf(v + EPS_);
  scale[c] = s;
  shift[c] = beta[c] - m*s;
}

// ---------------- agg -> normalized bf16 (empty segments -> 0) ----------------
__global__ void k_aggnorm(const float* __restrict__ agg, const int* __restrict__ counts,
                          const float* __restrict__ scale, const float* __restrict__ shift,
                          u32* __restrict__ out) {
  int i = blockIdx.x * 256 + threadIdx.x;       // pair index
  if (i >= M_NODE*C_/2) return;
  int n = (i*2) >> 8;
  int cbase = (i*2) & (C_-1);
  int cnt = counts[n];
  u32 r = 0;
  #pragma unroll
  for (int k = 0; k < 2; k++) {
    float val = (cnt > 0) ? fmaf(agg[(size_t)i*2 + k], scale[cbase + k], shift[cbase + k]) : 0.f;
    r |= ((u32)f2bf(val)) << (k*16);
  }
  out[i] = r;
}

// ---------------- u GEMM: y=relu(agg@Wu+b); stats; store y ----------------
__global__ __launch_bounds__(256)
void k_ugemm(const u16* __restrict__ A, const u16* __restrict__ WuT,
             const float* __restrict__ bu,
             float* __restrict__ yu, float* __restrict__ usum, float* __restrict__ usumsq)
{
  __shared__ __align__(16) u16 As[128*32];
  __shared__ __align__(16) u16 Bs[128*32];
  const int t  = threadIdx.x;
  const int n0 = blockIdx.x * 128;
  const int mb = blockIdx.y * 128;

  int r0 = mb + (t >> 2);      if (r0 >= M_NODE) r0 = 0;
  int r1 = mb + 64 + (t >> 2); if (r1 >= M_NODE) r1 = 0;
  const int ak = (((t & 3) ^ ((t >> 3) & 3)) << 3);
  const u16* asrc0 = A + (size_t)r0 * C_ + ak;
  const u16* asrc1 = A + (size_t)r1 * C_ + ak;
  const u16* bsrc0 = WuT + (size_t)(n0 + (t >> 2)) * C_ + ak;
  const u16* bsrc1 = WuT + (size_t)(n0 + 64 + (t >> 2)) * C_ + ak;

  const f32x4 zero = {0.f, 0.f, 0.f, 0.f};
  f32x4 acc[4][4];
  #pragma unroll
  for (int m = 0; m < 4; m++)
    #pragma unroll
    for (int n = 0; n < 4; n++) acc[m][n] = zero;

  const int lane = t & 63, wave = t >> 6;
  const int wr = wave >> 1, wc = wave & 1;
  const int lr = lane & 15, lch = lane >> 4;
  const int swz = (lr >> 1) & 3;

  for (int kk = 0; kk < 8; kk++) {
    const int k0 = kk * 32;
    async16(&As[t*8],        asrc0 + k0);
    async16(&As[(t+256)*8],  asrc1 + k0);
    async16(&Bs[t*8],        bsrc0 + k0);
    async16(&Bs[(t+256)*8],  bsrc1 + k0);
    __syncthreads();
    bf16x8 a[4], b[4];
    #pragma unroll
    for (int m = 0; m < 4; m++)
      a[m] = *(const bf16x8*)&As[(wr*64 + m*16 + lr)*32 + ((lch ^ swz) << 3)];
    #pragma unroll
    for (int n = 0; n < 4; n++)
      b[n] = *(const bf16x8*)&Bs[(wc*64 + n*16 + lr)*32 + ((lch ^ swz) << 3)];
    #pragma unroll
    for (int m = 0; m < 4; m++)
      #pragma unroll
      for (int n = 0; n < 4; n++)
        acc[m][n] = __builtin_amdgcn_mfma_f32_16x16x32_bf16(a[m], b[n], acc[m][n], 0, 0, 0);
    __syncthreads();
  }

  int gc[4]; float bias[4];
  #pragma unroll
  for (int n = 0; n < 4; n++) { int c = n0 + wc*64 + n*16 + lr; gc[n] = c; bias[n] = bu[c]; }
  float psum[4] = {0.f,0.f,0.f,0.f};
  float psq [4] = {0.f,0.f,0.f,0.f};
  #pragma unroll
  for (int m = 0; m < 4; m++) {
    #pragma unroll
    for (int j = 0; j < 4; j++) {
      int r = mb + wr*64 + m*16 + lch*4 + j;
      bool valid = r < M_NODE;
      #pragma unroll
      for (int n = 0; n < 4; n++) {
        float y = fmaxf(acc[m][n][j] + bias[n], 0.f);
        if (valid) {
          psum[n] += y;
          psq[n]  += y*y;
          yu[(size_t)r * C_ + gc[n]] = y;
        }
      }
    }
  }
  #pragma unroll
  for (int n = 0; n < 4; n++) {
    float s1 = psum[n], s2 = psq[n];
    s1 += __shfl_xor(s1, 16, 64);  s2 += __shfl_xor(s2, 16, 64);
    s1 += __shfl_xor(s1, 32, 64);  s2 += __shfl_xor(s2, 32, 64);
    if (lch == 0) { atomicAdd(&usum[gc[n]], s1); atomicAdd(&usumsq[gc[n]], s2); }
  }
}

// ---------------- final: BN affine + residual + transpose to [B][C][N] ----------------
__global__ void k_final(const float* __restrict__ yu, const float* __restrict__ feat,
                        const float* __restrict__ scale, const float* __restrict__ shift,
                        float* __restrict__ out) {
  __shared__ float tile[32][33];
  int tx = threadIdx.x & 31, ty = threadIdx.x >> 5;
  int b = blockIdx.z, c0 = blockIdx.y * 32, n0 = blockIdx.x * 32;
  #pragma unroll
  for (int i = 0; i < 4; i++) {
    int n = n0 + ty + i*8;
    tile[ty + i*8][tx] = (n < N_) ? yu[((size_t)(b*N_ + n))*C_ + c0 + tx] : 0.f;
  }
  __syncthreads();
  int n = n0 + tx;
  if (n < N_) {
    #pragma unroll
    for (int i = 0; i < 4; i++) {
      int c = c0 + ty + i*8;
      float v = tile[tx][ty + i*8] * scale[c] + shift[c];
      out[((size_t)(b*C_ + c))*N_ + n] = v + feat[((size_t)(b*C_ + c))*N_ + n];
    }
  }
}

extern "C" void kernel_launch(void* const* d_in, const int* in_sizes, int n_in,
                              void* d_out, int out_size, void* d_ws, size_t ws_size,
                              hipStream_t stream) {
  const float* xyz  = (const float*)d_in[0];
  const float* feat = (const float*)d_in[1];
  const int*   edges= (const int*)  d_in[2];
  const float* We   = (const float*)d_in[3];
  const float* be   = (const float*)d_in[4];
  const float* ge   = (const float*)d_in[5];
  const float* bte  = (const float*)d_in[6];
  const float* Wu   = (const float*)d_in[7];
  const float* bu   = (const float*)d_in[8];
  const float* gu   = (const float*)d_in[9];
  const float* btu  = (const float*)d_in[10];
  float* out = (float*)d_out;

  char* w = (char*)d_ws;
  size_t off = 0;
  auto carve = [&](size_t bytes) -> void* {
    void* p = w + off;
    off = (off + bytes + 511) & ~(size_t)511;
    return p;
  };
  u16*  vf      = (u16*) carve((size_t)M_NODE*C_*2);       // 10.24 MB
  u16*  WeT     = (u16*) carve((size_t)C_*C_*2);
  u16*  WuT     = (u16*) carve((size_t)C_*C_*2);
  float* z      = (float*)carve((size_t)M_NODE*C_*4);      // 20.48 MB
  float4* ed    = (float4*)carve((size_t)M_EDGE*16);       // 4.8 MB
  int*  counts  = (int*) carve((size_t)M_NODE*4);
  int*  offs    = (int*) carve((size_t)M_NODE*4);
  int*  cursor  = (int*) carve((size_t)M_NODE*4);
  float* agg    = (float*)carve((size_t)M_NODE*C_*4);      // 20.48 MB
  u32*  aggnorm = (u32*) carve((size_t)M_NODE*C_*2);       // 10.24 MB
  float* yu     = (float*)carve((size_t)M_NODE*C_*4);      // 20.48 MB
  float* stats  = (float*)carve(2048*4);
  float* esum = stats,        *esumsq = stats + 256;
  float* usum = stats + 512,  *usumsq = stats + 768;
  float* scale_e = stats + 1024, *shift_e = stats + 1280;
  float* scale_u = stats + 1536, *shift_u = stats + 1792;

  k_init<<<dim3((M_NODE + 255)/256), 256, 0, stream>>>(counts, stats);
  k_transpose_feat<<<dim3((N_+31)/32, C_/32, B_), 256, 0, stream>>>(feat, vf);
  k_transpose_w<<<dim3(C_/32, C_/32, 2), 256, 0, stream>>>(We, Wu, WeT, WuT);
  k_hist<<<dim3((M_EDGE + 255)/256), 256, 0, stream>>>(edges, counts);
  k_scan<<<1, 1024, 0, stream>>>(counts, offs, cursor);
  k_scatter<<<dim3((M_EDGE + 255)/256), 256, 0, stream>>>(edges, xyz, cursor, ed);
  k_zgemm<<<dim3(2, (M_NODE + 127)/128), 256, 0, stream>>>(vf, WeT, be, z);
  k_agg<<<dim3(M_NODE/4), 256, 0, stream>>>(z, ed, offs, counts, We, ge, agg, esum, esumsq);
  k_stats<<<1, 256, 0, stream>>>(esum, esumsq, ge, bte, (float)M_EDGE, scale_e, shift_e);
  k_aggnorm<<<dim3(M_NODE*C_/512), 256, 0, stream>>>(agg, counts, scale_e, shift_e, aggnorm);
  k_ugemm<<<dim3(2, (M_NODE + 127)/128), 256, 0, stream>>>(
      (const u16*)aggnorm, WuT, bu, yu, usum, usumsq);
  k_stats<<<1, 256, 0, stream>>>(usum, usumsq, gu, btu, (float)M_NODE, scale_u, shift_u);
  k_final<<<dim3((N_+31)/32, C_/32, B_), 256, 0, stream>>>(yu, feat, scale_u, shift_u, out);
}

// Round 4
// 200.112 us; speedup vs baseline: 1.2699x; 1.2699x over previous
//
#include <hip/hip_runtime.h>

#define B_ 2
#define N_ 10000
#define E_ 150000
#define C_ 256
#define M_EDGE (B_*E_)   // 300000
#define M_NODE (B_*N_)   // 20000
#define ED_CAP (M_EDGE + 3*M_NODE + 8)   // padded CSR capacity + tail slack
#define EPS_ 1e-5f

typedef unsigned short u16;
typedef unsigned int   u32;
typedef __attribute__((ext_vector_type(8))) __bf16 bf16x8;
typedef __attribute__((ext_vector_type(4))) float  f32x4;

__device__ __forceinline__ u16 f2bf(float x) {
  union { float f; u32 u; } v; v.f = x;
  u32 r = v.u + 0x7FFFu + ((v.u >> 16) & 1u);   // RNE
  return (u16)(r >> 16);
}

__device__ __forceinline__ void async16(void* lds, const void* g) {
  __builtin_amdgcn_global_load_lds(
      (const __attribute__((address_space(1))) void*)g,
      (__attribute__((address_space(3))) void*)lds, 16, 0, 0);
}

// ---------------- init: zero counts + stats ----------------
__global__ void k_init(int* __restrict__ counts, float* __restrict__ stats) {
  int i = blockIdx.x * 256 + threadIdx.x;
  if (i < M_NODE) counts[i] = 0;
  if (i < 1024) stats[i] = 0.f;
}

// ---------------- features [B][C][N] f32 -> vf [B][N][C] bf16 ----------------
__global__ void k_transpose_feat(const float* __restrict__ f, u16* __restrict__ vf) {
  __shared__ float tile[32][33];
  int tx = threadIdx.x & 31, ty = threadIdx.x >> 5;
  int b = blockIdx.z, c0 = blockIdx.y * 32, n0 = blockIdx.x * 32;
  #pragma unroll
  for (int i = 0; i < 4; i++) {
    int c = c0 + ty + i*8, n = n0 + tx;
    tile[ty + i*8][tx] = (n < N_) ? f[((size_t)(b*C_ + c))*N_ + n] : 0.f;
  }
  __syncthreads();
  #pragma unroll
  for (int i = 0; i < 4; i++) {
    int n = n0 + ty + i*8, c = c0 + tx;
    if (n < N_) vf[((size_t)(b*N_ + n))*C_ + c] = f2bf(tile[tx][ty + i*8]);
  }
}

// ---------------- W_e[0:256][:], W_u -> transposed bf16 [Cout][K] ----------------
__global__ void k_transpose_w(const float* __restrict__ We, const float* __restrict__ Wu,
                              u16* __restrict__ WeT, u16* __restrict__ WuT) {
  __shared__ float tile[32][33];
  const float* src = blockIdx.z ? Wu : We;
  u16* dst = blockIdx.z ? WuT : WeT;
  int tx = threadIdx.x & 31, ty = threadIdx.x >> 5;
  int r0 = blockIdx.y * 32, c0 = blockIdx.x * 32;
  #pragma unroll
  for (int i = 0; i < 4; i++)
    tile[ty + i*8][tx] = src[(size_t)(r0 + ty + i*8)*C_ + c0 + tx];
  __syncthreads();
  #pragma unroll
  for (int i = 0; i < 4; i++)
    dst[(size_t)(c0 + ty + i*8)*C_ + r0 + tx] = f2bf(tile[tx][ty + i*8]);
}

// ---------------- histogram of dst ----------------
__global__ void k_hist(const int* __restrict__ edges, int* __restrict__ counts) {
  int i = blockIdx.x * 256 + threadIdx.x;
  if (i >= M_EDGE) return;
  int b = (i >= E_) ? 1 : 0;
  int e = i - b * E_;
  int d = edges[(size_t)(b*2 + 1)*E_ + e];
  atomicAdd(&counts[b*N_ + d], 1);
}

// ---------------- exclusive scan of PADDED counts (single block) ----------------
__global__ __launch_bounds__(1024)
void k_scan(const int* __restrict__ counts, int* __restrict__ offs, int* __restrict__ cursor) {
  __shared__ int part[1024];
  int t = threadIdx.x;
  int base = t * 20;
  int vals[20];
  if (t < 1000) {
    #pragma unroll
    for (int j = 0; j < 5; j++)
      *(int4*)&vals[j*4] = *(const int4*)&counts[base + j*4];
  } else {
    #pragma unroll
    for (int i = 0; i < 20; i++) vals[i] = 0;
  }
  int local[20];
  int s = 0;
  #pragma unroll
  for (int i = 0; i < 20; i++) {
    int pv = (vals[i] + 3) & ~3;          // pad each node to multiple of 4
    local[i] = s; s += pv;
  }
  part[t] = s;
  __syncthreads();
  for (int d = 1; d < 1024; d <<= 1) {
    int v = (t >= d) ? part[t - d] : 0;
    __syncthreads();
    part[t] += v;
    __syncthreads();
  }
  int excl = (t == 0) ? 0 : part[t - 1];
  if (t < 1000) {
    #pragma unroll
    for (int j = 0; j < 5; j++) {
      int4 o;
      o.x = excl + local[j*4 + 0];
      o.y = excl + local[j*4 + 1];
      o.z = excl + local[j*4 + 2];
      o.w = excl + local[j*4 + 3];
      *(int4*)&offs[base + j*4]   = o;
      *(int4*)&cursor[base + j*4] = o;
    }
  }
  if (t == 1023) offs[M_NODE] = part[1023];   // total padded size
}

// ---------------- scatter edges into padded CSR slots ----------------
__global__ void k_scatter(const int* __restrict__ edges, const float* __restrict__ xyz,
                          int* __restrict__ cursor, float4* __restrict__ ed) {
  int i = blockIdx.x * 256 + threadIdx.x;
  if (i >= M_EDGE) return;
  int b = (i >= E_) ? 1 : 0;
  int e = i - b * E_;
  int s = edges[(size_t)(b*2 + 0)*E_ + e];
  int d = edges[(size_t)(b*2 + 1)*E_ + e];
  const float* ps = xyz + ((size_t)(b*N_ + s))*3;
  const float* pd = xyz + ((size_t)(b*N_ + d))*3;
  int pos = atomicAdd(&cursor[b*N_ + d], 1);
  ed[pos] = make_float4(ps[0]-pd[0], ps[1]-pd[1], ps[2]-pd[2],
                        __int_as_float(b*N_ + s));
}

// ---------------- fill padding slots (dup of first edge) + array tail ----------------
__global__ void k_pad(const int* __restrict__ offs, const int* __restrict__ counts,
                      float4* __restrict__ ed) {
  int i = blockIdx.x * 256 + threadIdx.x;
  if (i < M_NODE) {
    int cnt = counts[i];
    if (cnt > 0) {
      int pad = (-cnt) & 3;
      if (pad) {
        int start = offs[i];
        float4 f = ed[start];
        for (int k = 0; k < pad; k++) ed[start + cnt + k] = f;
      }
    }
  }
  int total = offs[M_NODE];
  int pos = total + i;
  if (pos < ED_CAP)
    ed[pos] = make_float4(0.f, 0.f, 0.f, __int_as_float(0));
}

// ---------------- z GEMM: z = vf @ We[0:256] + be (fp16 out) ----------------
__global__ __launch_bounds__(256)
void k_zgemm(const u16* __restrict__ A, const u16* __restrict__ WeT,
             const float* __restrict__ be, u16* __restrict__ zh)
{
  __shared__ __align__(16) u16 As[128*32];
  __shared__ __align__(16) u16 Bs[128*32];
  const int t  = threadIdx.x;
  const int n0 = blockIdx.x * 128;
  const int mb = blockIdx.y * 128;

  int r0 = mb + (t >> 2);      if (r0 >= M_NODE) r0 = 0;
  int r1 = mb + 64 + (t >> 2); if (r1 >= M_NODE) r1 = 0;
  const int ak = (((t & 3) ^ ((t >> 3) & 3)) << 3);
  const u16* asrc0 = A + (size_t)r0 * C_ + ak;
  const u16* asrc1 = A + (size_t)r1 * C_ + ak;
  const u16* bsrc0 = WeT + (size_t)(n0 + (t >> 2)) * C_ + ak;
  const u16* bsrc1 = WeT + (size_t)(n0 + 64 + (t >> 2)) * C_ + ak;

  const f32x4 zero = {0.f, 0.f, 0.f, 0.f};
  f32x4 acc[4][4];
  #pragma unroll
  for (int m = 0; m < 4; m++)
    #pragma unroll
    for (int n = 0; n < 4; n++) acc[m][n] = zero;

  const int lane = t & 63, wave = t >> 6;
  const int wr = wave >> 1, wc = wave & 1;
  const int lr = lane & 15, lch = lane >> 4;
  const int swz = (lr >> 1) & 3;

  for (int kk = 0; kk < 8; kk++) {
    const int k0 = kk * 32;
    async16(&As[t*8],        asrc0 + k0);
    async16(&As[(t+256)*8],  asrc1 + k0);
    async16(&Bs[t*8],        bsrc0 + k0);
    async16(&Bs[(t+256)*8],  bsrc1 + k0);
    __syncthreads();
    bf16x8 a[4], b[4];
    #pragma unroll
    for (int m = 0; m < 4; m++)
      a[m] = *(const bf16x8*)&As[(wr*64 + m*16 + lr)*32 + ((lch ^ swz) << 3)];
    #pragma unroll
    for (int n = 0; n < 4; n++)
      b[n] = *(const bf16x8*)&Bs[(wc*64 + n*16 + lr)*32 + ((lch ^ swz) << 3)];
    #pragma unroll
    for (int m = 0; m < 4; m++)
      #pragma unroll
      for (int n = 0; n < 4; n++)
        acc[m][n] = __builtin_amdgcn_mfma_f32_16x16x32_bf16(a[m], b[n], acc[m][n], 0, 0, 0);
    __syncthreads();
  }

  int gc[4]; float bias[4];
  #pragma unroll
  for (int n = 0; n < 4; n++) { int c = n0 + wc*64 + n*16 + lr; gc[n] = c; bias[n] = be[c]; }
  #pragma unroll
  for (int m = 0; m < 4; m++) {
    #pragma unroll
    for (int j = 0; j < 4; j++) {
      int r = mb + wr*64 + m*16 + lch*4 + j;
      if (r < M_NODE) {
        #pragma unroll
        for (int n = 0; n < 4; n++) {
          _Float16 h = (_Float16)(acc[m][n][j] + bias[n]);
          zh[(size_t)r * C_ + gc[n]] = *(const u16*)&h;
        }
      }
    }
  }
}

// ---------------- aggregation: chunk-4 pipelined gather over fp16 z ----------------
__global__ __launch_bounds__(256)
void k_agg(const u16* __restrict__ zh, const float4* __restrict__ ed,
           const int* __restrict__ offs, const int* __restrict__ counts,
           const float* __restrict__ We, const float* __restrict__ ge,
           float* __restrict__ agg, float* __restrict__ esum, float* __restrict__ esumsq)
{
  const int lane = threadIdx.x & 63, wave = threadIdx.x >> 6;
  const int c0 = lane * 4;
  const float4 w0 = *(const float4*)&We[256*C_ + c0];
  const float4 w1 = *(const float4*)&We[257*C_ + c0];
  const float4 w2 = *(const float4*)&We[258*C_ + c0];
  const float4 gs = *(const float4*)&ge[c0];
  const u16* zp = zh + c0;

  float ps[4] = {0.f,0.f,0.f,0.f};
  float pq[4] = {0.f,0.f,0.f,0.f};

  for (int n = blockIdx.x * 4 + wave; n < M_NODE; n += M_NODE/2) {
    const int start = offs[n], cnt = counts[n];
    float mx[4] = {-1.f,-1.f,-1.f,-1.f};        // y >= 0
    float mn[4] = {1e30f,1e30f,1e30f,1e30f};

    if (cnt > 0) {
      const float4* rp = ed + start;
      const int nch = (cnt + 3) >> 2;

      auto zld = [&](const float4& r) -> uint2 {
        return *(const uint2*)(zp + (size_t)__float_as_int(r.w) * C_);
      };
      auto proc = [&](const float4& d, uint2 zu, bool g) {
        union { u32 w; _Float16 h[2]; } ux, uy;
        ux.w = zu.x; uy.w = zu.y;
        float z0 = (float)ux.h[0], z1 = (float)ux.h[1];
        float z2 = (float)uy.h[0], z3 = (float)uy.h[1];
        float y0 = fmaxf(fmaf(d.z, w2.x, fmaf(d.y, w1.x, fmaf(d.x, w0.x, z0))), 0.f);
        float y1 = fmaxf(fmaf(d.z, w2.y, fmaf(d.y, w1.y, fmaf(d.x, w0.y, z1))), 0.f);
        float y2 = fmaxf(fmaf(d.z, w2.z, fmaf(d.y, w1.z, fmaf(d.x, w0.z, z2))), 0.f);
        float y3 = fmaxf(fmaf(d.z, w2.w, fmaf(d.y, w1.w, fmaf(d.x, w0.w, z3))), 0.f);
        mx[0]=fmaxf(mx[0],y0); mn[0]=fminf(mn[0],y0);
        mx[1]=fmaxf(mx[1],y1); mn[1]=fminf(mn[1],y1);
        mx[2]=fmaxf(mx[2],y2); mn[2]=fminf(mn[2],y2);
        mx[3]=fmaxf(mx[3],y3); mn[3]=fminf(mn[3],y3);
        if (g) {
          ps[0]+=y0; pq[0]=fmaf(y0,y0,pq[0]);
          ps[1]+=y1; pq[1]=fmaf(y1,y1,pq[1]);
          ps[2]+=y2; pq[2]=fmaf(y2,y2,pq[2]);
          ps[3]+=y3; pq[3]=fmaf(y3,y3,pq[3]);
        }
      };

      // prologue: chunk0 records + z, chunk1 records
      float4 ra0 = rp[0], ra1 = rp[1], ra2 = rp[2], ra3 = rp[3];
      uint2  za0 = zld(ra0), za1 = zld(ra1), za2 = zld(ra2), za3 = zld(ra3);
      float4 rb0 = rp[4], rb1 = rp[5], rb2 = rp[6], rb3 = rp[7];
      uint2  zb0 = {0,0}, zb1 = {0,0}, zb2 = {0,0}, zb3 = {0,0};

      for (int ch = 0; ch < nch; ch++) {
        const bool more = (ch + 1) < nch;
        float4 rc0, rc1, rc2, rc3;
        if (more) {
          // issue z for next chunk (addresses already in regs) + records two ahead
          zb0 = zld(rb0); zb1 = zld(rb1); zb2 = zld(rb2); zb3 = zld(rb3);
          const float4* rn = rp + ch*4 + 8;
          rc0 = rn[0]; rc1 = rn[1]; rc2 = rn[2]; rc3 = rn[3];
        }
        const int rem = cnt - ch*4;
        if (rem >= 4) {
          proc(ra0, za0, true);
          proc(ra1, za1, true);
          proc(ra2, za2, true);
          proc(ra3, za3, true);
        } else {                       // tail chunk: padding dups excluded from stats
          proc(ra0, za0, true);
          proc(ra1, za1, rem > 1);
          proc(ra2, za2, rem > 2);
          proc(ra3, za3, false);
        }
        if (more) {
          ra0=rb0; ra1=rb1; ra2=rb2; ra3=rb3;
          rb0=rc0; rb1=rc1; rb2=rc2; rb3=rc3;
          za0=zb0; za1=zb1; za2=zb2; za3=zb3;
        }
      }
    }

    float4 outv;
    outv.x = (gs.x >= 0.f) ? mx[0] : mn[0];
    outv.y = (gs.y >= 0.f) ? mx[1] : mn[1];
    outv.z = (gs.z >= 0.f) ? mx[2] : mn[2];
    outv.w = (gs.w >= 0.f) ? mx[3] : mn[3];
    *(float4*)&agg[(size_t)n * C_ + c0] = outv;
  }

  // block-level stats reduction -> one atomicAdd per col
  __shared__ float red[4][256];
  #pragma unroll
  for (int j = 0; j < 4; j++) red[wave][c0 + j] = ps[j];
  __syncthreads();
  if (threadIdx.x < 256) {
    float s = red[0][threadIdx.x] + red[1][threadIdx.x] + red[2][threadIdx.x] + red[3][threadIdx.x];
    atomicAdd(&esum[threadIdx.x], s);
  }
  __syncthreads();
  #pragma unroll
  for (int j = 0; j < 4; j++) red[wave][c0 + j] = pq[j];
  __syncthreads();
  if (threadIdx.x < 256) {
    float s = red[0][threadIdx.x] + red[1][threadIdx.x] + red[2][threadIdx.x] + red[3][threadIdx.x];
    atomicAdd(&esumsq[threadIdx.x], s);
  }
}

// ---------------- BN stats -> scale/shift ----------------
__global__ void k_stats(const float* __restrict__ sum, const float* __restrict__ sumsq,
                        const float* __restrict__ g, const float* __restrict__ beta,
                        float cnt, float* __restrict__ scale, float* __restrict__ shift) {
  int c = threadIdx.x;
  float m = sum[c] / cnt;
  float v = sumsq[c] / cnt - m*m;
  v = fmaxf(v, 0.f);
  float s = g[c] * rsqrtf(v + EPS_);
  scale[c] = s;
  shift[c] = beta[c] - m*s;
}

// ---------------- agg -> normalized bf16 (empty segments -> 0) ----------------
__global__ void k_aggnorm(const float* __restrict__ agg, const int* __restrict__ counts,
                          const float* __restrict__ scale, const float* __restrict__ shift,
                          u32* __restrict__ out) {
  int i = blockIdx.x * 256 + threadIdx.x;       // pair index
  if (i >= M_NODE*C_/2) return;
  int n = (i*2) >> 8;
  int cbase = (i*2) & (C_-1);
  int cnt = counts[n];
  u32 r = 0;
  #pragma unroll
  for (int k = 0; k < 2; k++) {
    float val = (cnt > 0) ? fmaf(agg[(size_t)i*2 + k], scale[cbase + k], shift[cbase + k]) : 0.f;
    r |= ((u32)f2bf(val)) << (k*16);
  }
  out[i] = r;
}

// ---------------- u GEMM: y=relu(agg@Wu+b); stats; store y ----------------
__global__ __launch_bounds__(256)
void k_ugemm(const u16* __restrict__ A, const u16* __restrict__ WuT,
             const float* __restrict__ bu,
             float* __restrict__ yu, float* __restrict__ usum, float* __restrict__ usumsq)
{
  __shared__ __align__(16) u16 As[128*32];
  __shared__ __align__(16) u16 Bs[128*32];
  const int t  = threadIdx.x;
  const int n0 = blockIdx.x * 128;
  const int mb = blockIdx.y * 128;

  int r0 = mb + (t >> 2);      if (r0 >= M_NODE) r0 = 0;
  int r1 = mb + 64 + (t >> 2); if (r1 >= M_NODE) r1 = 0;
  const int ak = (((t & 3) ^ ((t >> 3) & 3)) << 3);
  const u16* asrc0 = A + (size_t)r0 * C_ + ak;
  const u16* asrc1 = A + (size_t)r1 * C_ + ak;
  const u16* bsrc0 = WuT + (size_t)(n0 + (t >> 2)) * C_ + ak;
  const u16* bsrc1 = WuT + (size_t)(n0 + 64 + (t >> 2)) * C_ + ak;

  const f32x4 zero = {0.f, 0.f, 0.f, 0.f};
  f32x4 acc[4][4];
  #pragma unroll
  for (int m = 0; m < 4; m++)
    #pragma unroll
    for (int n = 0; n < 4; n++) acc[m][n] = zero;

  const int lane = t & 63, wave = t >> 6;
  const int wr = wave >> 1, wc = wave & 1;
  const int lr = lane & 15, lch = lane >> 4;
  const int swz = (lr >> 1) & 3;

  for (int kk = 0; kk < 8; kk++) {
    const int k0 = kk * 32;
    async16(&As[t*8],        asrc0 + k0);
    async16(&As[(t+256)*8],  asrc1 + k0);
    async16(&Bs[t*8],        bsrc0 + k0);
    async16(&Bs[(t+256)*8],  bsrc1 + k0);
    __syncthreads();
    bf16x8 a[4], b[4];
    #pragma unroll
    for (int m = 0; m < 4; m++)
      a[m] = *(const bf16x8*)&As[(wr*64 + m*16 + lr)*32 + ((lch ^ swz) << 3)];
    #pragma unroll
    for (int n = 0; n < 4; n++)
      b[n] = *(const bf16x8*)&Bs[(wc*64 + n*16 + lr)*32 + ((lch ^ swz) << 3)];
    #pragma unroll
    for (int m = 0; m < 4; m++)
      #pragma unroll
      for (int n = 0; n < 4; n++)
        acc[m][n] = __builtin_amdgcn_mfma_f32_16x16x32_bf16(a[m], b[n], acc[m][n], 0, 0, 0);
    __syncthreads();
  }

  int gc[4]; float bias[4];
  #pragma unroll
  for (int n = 0; n < 4; n++) { int c = n0 + wc*64 + n*16 + lr; gc[n] = c; bias[n] = bu[c]; }
  float psum[4] = {0.f,0.f,0.f,0.f};
  float psq [4] = {0.f,0.f,0.f,0.f};
  #pragma unroll
  for (int m = 0; m < 4; m++) {
    #pragma unroll
    for (int j = 0; j < 4; j++) {
      int r = mb + wr*64 + m*16 + lch*4 + j;
      bool valid = r < M_NODE;
      #pragma unroll
      for (int n = 0; n < 4; n++) {
        float y = fmaxf(acc[m][n][j] + bias[n], 0.f);
        if (valid) {
          psum[n] += y;
          psq[n]  += y*y;
          yu[(size_t)r * C_ + gc[n]] = y;
        }
      }
    }
  }
  #pragma unroll
  for (int n = 0; n < 4; n++) {
    float s1 = psum[n], s2 = psq[n];
    s1 += __shfl_xor(s1, 16, 64);  s2 += __shfl_xor(s2, 16, 64);
    s1 += __shfl_xor(s1, 32, 64);  s2 += __shfl_xor(s2, 32, 64);
    if (lch == 0) { atomicAdd(&usum[gc[n]], s1); atomicAdd(&usumsq[gc[n]], s2); }
  }
}

// ---------------- final: BN affine + residual + transpose to [B][C][N] ----------------
__global__ void k_final(const float* __restrict__ yu, const float* __restrict__ feat,
                        const float* __restrict__ scale, const float* __restrict__ shift,
                        float* __restrict__ out) {
  __shared__ float tile[32][33];
  int tx = threadIdx.x & 31, ty = threadIdx.x >> 5;
  int b = blockIdx.z, c0 = blockIdx.y * 32, n0 = blockIdx.x * 32;
  #pragma unroll
  for (int i = 0; i < 4; i++) {
    int n = n0 + ty + i*8;
    tile[ty + i*8][tx] = (n < N_) ? yu[((size_t)(b*N_ + n))*C_ + c0 + tx] : 0.f;
  }
  __syncthreads();
  int n = n0 + tx;
  if (n < N_) {
    #pragma unroll
    for (int i = 0; i < 4; i++) {
      int c = c0 + ty + i*8;
      float v = tile[tx][ty + i*8] * scale[c] + shift[c];
      out[((size_t)(b*C_ + c))*N_ + n] = v + feat[((size_t)(b*C_ + c))*N_ + n];
    }
  }
}

extern "C" void kernel_launch(void* const* d_in, const int* in_sizes, int n_in,
                              void* d_out, int out_size, void* d_ws, size_t ws_size,
                              hipStream_t stream) {
  const float* xyz  = (const float*)d_in[0];
  const float* feat = (const float*)d_in[1];
  const int*   edges= (const int*)  d_in[2];
  const float* We   = (const float*)d_in[3];
  const float* be   = (const float*)d_in[4];
  const float* ge   = (const float*)d_in[5];
  const float* bte  = (const float*)d_in[6];
  const float* Wu   = (const float*)d_in[7];
  const float* bu   = (const float*)d_in[8];
  const float* gu   = (const float*)d_in[9];
  const float* btu  = (const float*)d_in[10];
  float* out = (float*)d_out;

  char* w = (char*)d_ws;
  size_t off = 0;
  auto carve = [&](size_t bytes) -> void* {
    void* p = w + off;
    off = (off + bytes + 511) & ~(size_t)511;
    return p;
  };
  u16*  vf      = (u16*) carve((size_t)M_NODE*C_*2);       // 10.24 MB
  u16*  WeT     = (u16*) carve((size_t)C_*C_*2);
  u16*  WuT     = (u16*) carve((size_t)C_*C_*2);
  u16*  zh      = (u16*) carve((size_t)M_NODE*C_*2);       // 10.24 MB (fp16)
  float4* ed    = (float4*)carve((size_t)ED_CAP*16);       // 5.76 MB
  int*  counts  = (int*) carve((size_t)M_NODE*4);
  int*  offs    = (int*) carve((size_t)(M_NODE+1)*4);
  int*  cursor  = (int*) carve((size_t)M_NODE*4);
  float* agg    = (float*)carve((size_t)M_NODE*C_*4);      // 20.48 MB
  u32*  aggnorm = (u32*) carve((size_t)M_NODE*C_*2);       // 10.24 MB
  float* yu     = (float*)carve((size_t)M_NODE*C_*4);      // 20.48 MB
  float* stats  = (float*)carve(2048*4);
  float* esum = stats,        *esumsq = stats + 256;
  float* usum = stats + 512,  *usumsq = stats + 768;
  float* scale_e = stats + 1024, *shift_e = stats + 1280;
  float* scale_u = stats + 1536, *shift_u = stats + 1792;

  k_init<<<dim3((M_NODE + 255)/256), 256, 0, stream>>>(counts, stats);
  k_transpose_feat<<<dim3((N_+31)/32, C_/32, B_), 256, 0, stream>>>(feat, vf);
  k_transpose_w<<<dim3(C_/32, C_/32, 2), 256, 0, stream>>>(We, Wu, WeT, WuT);
  k_hist<<<dim3((M_EDGE + 255)/256), 256, 0, stream>>>(edges, counts);
  k_scan<<<1, 1024, 0, stream>>>(counts, offs, cursor);
  k_scatter<<<dim3((M_EDGE + 255)/256), 256, 0, stream>>>(edges, xyz, cursor, ed);
  k_pad<<<dim3(240), 256, 0, stream>>>(offs, counts, ed);
  k_zgemm<<<dim3(2, (M_NODE + 127)/128), 256, 0, stream>>>(vf, WeT, be, zh);
  k_agg<<<dim3(M_NODE/8), 256, 0, stream>>>(zh, ed, offs, counts, We, ge, agg, esum, esumsq);
  k_stats<<<1, 256, 0, stream>>>(esum, esumsq, ge, bte, (float)M_EDGE, scale_e, shift_e);
  k_aggnorm<<<dim3(M_NODE*C_/512), 256, 0, stream>>>(agg, counts, scale_e, shift_e, aggnorm);
  k_ugemm<<<dim3(2, (M_NODE + 127)/128), 256, 0, stream>>>(
      (const u16*)aggnorm, WuT, bu, yu, usum, usumsq);
  k_stats<<<1, 256, 0, stream>>>(usum, usumsq, gu, btu, (float)M_NODE, scale_u, shift_u);
  k_final<<<dim3((N_+31)/32, C_/32, B_), 256, 0, stream>>>(yu, feat, scale_u, shift_u, out);
}